// Round 4
// baseline (145.192 us; speedup 1.0000x reference)
//
#include <hip/hip_runtime.h>

#define N_EMB 8192
#define DIM   1024
#define NPAIR 65536
#define MARGIN 1.0f

// -------- Kernel A: row inverse norms (+ zero the accumulator) --------
// One block (256 threads) per row; each thread loads one float4 (4 floats).
__global__ __launch_bounds__(256) void norms_kernel(const float* __restrict__ emb,
                                                    float* __restrict__ rnorm,
                                                    double* __restrict__ acc) {
    const int row  = blockIdx.x;
    const int tid  = threadIdx.x;
    const float4 v = reinterpret_cast<const float4*>(emb + (size_t)row * DIM)[tid];
    float s = v.x * v.x + v.y * v.y + v.z * v.z + v.w * v.w;

    // wave reduce (64 lanes)
    #pragma unroll
    for (int off = 32; off > 0; off >>= 1) s += __shfl_xor(s, off);

    __shared__ float part[4];
    const int wave = tid >> 6;
    const int lane = tid & 63;
    if (lane == 0) part[wave] = s;
    __syncthreads();
    if (tid == 0) {
        float tot = part[0] + part[1] + part[2] + part[3];
        rnorm[row] = 1.0f / sqrtf(tot);
        if (row == 0) *acc = 0.0;   // zero accumulator (ws is poisoned each call)
    }
}

// -------- Kernel B: pair gather + dot + hinge loss + reduce --------
// One wave per pair per iteration. Lane l reads float4 at l, l+64, l+128, l+192
// of each row (fully coalesced: 64 lanes x 16B = 1KB per instruction).
__global__ __launch_bounds__(256) void pair_kernel(const float* __restrict__ emb,
                                                   const float* __restrict__ rnorm,
                                                   const int* __restrict__ ind1,
                                                   const int* __restrict__ ind2,
                                                   const int* __restrict__ tgt,
                                                   double* __restrict__ acc) {
    const int lane   = threadIdx.x & 63;
    const int wave   = (blockIdx.x * blockDim.x + threadIdx.x) >> 6;
    const int nwaves = (gridDim.x * blockDim.x) >> 6;

    float wsum = 0.0f;

    for (int p = wave; p < NPAIR; p += nwaves) {
        const int a = ind1[p];
        const int b = ind2[p];
        const float4* ra = reinterpret_cast<const float4*>(emb + (size_t)a * DIM);
        const float4* rb = reinterpret_cast<const float4*>(emb + (size_t)b * DIM);

        // issue all 8 loads before any use (ILP to hide L2/L3 latency)
        const float4 a0 = ra[lane];
        const float4 a1 = ra[lane + 64];
        const float4 a2 = ra[lane + 128];
        const float4 a3 = ra[lane + 192];
        const float4 b0 = rb[lane];
        const float4 b1 = rb[lane + 64];
        const float4 b2 = rb[lane + 128];
        const float4 b3 = rb[lane + 192];

        float s = a0.x * b0.x;
        s = fmaf(a0.y, b0.y, s);
        s = fmaf(a0.z, b0.z, s);
        s = fmaf(a0.w, b0.w, s);
        s = fmaf(a1.x, b1.x, s);
        s = fmaf(a1.y, b1.y, s);
        s = fmaf(a1.z, b1.z, s);
        s = fmaf(a1.w, b1.w, s);
        s = fmaf(a2.x, b2.x, s);
        s = fmaf(a2.y, b2.y, s);
        s = fmaf(a2.z, b2.z, s);
        s = fmaf(a2.w, b2.w, s);
        s = fmaf(a3.x, b3.x, s);
        s = fmaf(a3.y, b3.y, s);
        s = fmaf(a3.z, b3.z, s);
        s = fmaf(a3.w, b3.w, s);

        // wave reduce -> all lanes hold full dot
        #pragma unroll
        for (int off = 32; off > 0; off >>= 1) s += __shfl_xor(s, off);

        const float dist = 1.0f - s * rnorm[a] * rnorm[b];
        const float t    = (float)tgt[p];
        const float loss = t * dist + (1.0f - t) * fmaxf(MARGIN - dist, 0.0f);
        if (lane == 0) wsum += loss;
    }

    // block reduce (lane 0 of each of 4 waves), one double atomic per block
    __shared__ float part[4];
    if (lane == 0) part[threadIdx.x >> 6] = wsum;
    __syncthreads();
    if (threadIdx.x == 0) {
        const float bs = part[0] + part[1] + part[2] + part[3];
        atomicAdd(acc, (double)bs);
    }
}

// -------- Kernel C: finalize mean --------
__global__ void finalize_kernel(const double* __restrict__ acc, float* __restrict__ out) {
    out[0] = (float)(acc[0] / (double)NPAIR);
}

extern "C" void kernel_launch(void* const* d_in, const int* in_sizes, int n_in,
                              void* d_out, int out_size, void* d_ws, size_t ws_size,
                              hipStream_t stream) {
    const float* emb  = (const float*)d_in[0];
    const int*   ind1 = (const int*)d_in[1];
    const int*   ind2 = (const int*)d_in[2];
    const int*   tgt  = (const int*)d_in[3];
    float*       out  = (float*)d_out;

    // ws layout: [0 .. N_EMB floats) rnorm, then 8-byte-aligned double acc
    float*  rnorm = (float*)d_ws;
    double* acc   = (double*)((char*)d_ws + (size_t)N_EMB * sizeof(float));

    norms_kernel<<<N_EMB, 256, 0, stream>>>(emb, rnorm, acc);

    // 2048 blocks x 256 threads = 8192 waves -> 8 pairs/wave; 32 waves/CU occupancy
    pair_kernel<<<2048, 256, 0, stream>>>(emb, rnorm, ind1, ind2, tgt, acc);

    finalize_kernel<<<1, 1, 0, stream>>>(acc, out);
}